// Round 14
// baseline (141.857 us; speedup 1.0000x reference)
//
#include <hip/hip_runtime.h>
#include <hip/hip_bf16.h>

// Problem constants: B=2, S=2048, D=1024, H=16, dk=64
#define S_LEN 2048
#define S_PAD 2112   // Vt row stride: 4224B = 16.5 x 256B lines -> breaks L2
                     // channel aliasing (4096B stride camps all rows on one channel)
#define D_DIM 1024
#define N_HEADS 16
#define M_ROWS 4096  // B*S

typedef __bf16 bf16x8 __attribute__((ext_vector_type(8)));
typedef float f32x4 __attribute__((ext_vector_type(4)));
typedef float f32x16 __attribute__((ext_vector_type(16)));
typedef unsigned short ushortx8 __attribute__((ext_vector_type(8)));
typedef unsigned int uintx4 __attribute__((ext_vector_type(4)));

__device__ __forceinline__ unsigned short f2bf(float f) {
  unsigned int u = __builtin_bit_cast(unsigned int, f);
  u += 0x7fffu + ((u >> 16) & 1u);   // RNE
  return (unsigned short)(u >> 16);
}

// v_cvt_pk_bf16_f32: packs 2 f32 -> u32 (lo|hi<<16), RNE. No builtin on gfx950.
__device__ __forceinline__ unsigned int cvtpk(float lo, float hi) {
  unsigned int r;
  asm("v_cvt_pk_bf16_f32 %0, %1, %2" : "=v"(r) : "v"(lo), "v"(hi));
  return r;
}

// v_permlane32_swap_b32 a, b: a.lanes[32:63] <-> b.lanes[0:31]
__device__ __forceinline__ void pl32swap(unsigned int& a, unsigned int& b) {
  asm("v_permlane32_swap_b32 %0, %1" : "+v"(a), "+v"(b));
}

__device__ __forceinline__ float bfhi(unsigned int u) {   // low 16 bits -> f32
  return __builtin_bit_cast(float, u << 16);
}

__device__ __forceinline__ bf16x8 load8(const unsigned short* p) {
  return __builtin_bit_cast(bf16x8, *(const ushortx8*)p);
}

__device__ __forceinline__ void gload16(const unsigned short* g, unsigned short* l) {
  __builtin_amdgcn_global_load_lds((const __attribute__((address_space(1))) void*)g,
                                   (__attribute__((address_space(3))) void*)l,
                                   16, 0, 0);
}

// ---------------- fp32 -> bf16 convert (fused: x + 4 weights) ----------------
__global__ void cvt5_kernel(const float* __restrict__ s0, const float* __restrict__ s1,
                            const float* __restrict__ s2, const float* __restrict__ s3,
                            const float* __restrict__ s4,
                            unsigned short* __restrict__ d0, unsigned short* __restrict__ d1,
                            unsigned short* __restrict__ d2, unsigned short* __restrict__ d3,
                            unsigned short* __restrict__ d4,
                            int n4x, int n4w) {
  const int y = blockIdx.y;
  const float* s = (y == 0) ? s0 : (y == 1) ? s1 : (y == 2) ? s2 : (y == 3) ? s3 : s4;
  unsigned short* d = (y == 0) ? d0 : (y == 1) ? d1 : (y == 2) ? d2 : (y == 3) ? d3 : d4;
  const int n4 = (y == 0) ? n4x : n4w;
  int i = blockIdx.x * blockDim.x + threadIdx.x;
  if (i < n4) {
    float4 f = ((const float4*)s)[i];
    unsigned int u0 = cvtpk(f.x, f.y), u1 = cvtpk(f.z, f.w);
    unsigned long long packed = (unsigned long long)u0 | ((unsigned long long)u1 << 32);
    ((unsigned long long*)d)[i] = packed;
  }
}

// ---------------- bf16 GEMM: C = A[M,K] * B[N,K]^T ----------------
// mode 0: fp32 row-major [M][N] output
// mode 1: bf16 [B,H,S,64] output (Q,K); Q (z==0) pre-scaled by log2e/sqrt(dk)
// mode 2: bf16 [B,H,64,S_PAD] output (V transposed, padded stride)
__global__ __launch_bounds__(256) void gemm_bt(
    const unsigned short* __restrict__ A,
    const unsigned short* __restrict__ B0,
    const unsigned short* __restrict__ B1,
    const unsigned short* __restrict__ B2,
    void* __restrict__ C0, void* __restrict__ C1, void* __restrict__ C2,
    int M, int N, int K, int modesel)
{
  __shared__ __align__(16) unsigned short At[128 * 64];
  __shared__ __align__(16) unsigned short Bt[128 * 64];

  const int z = blockIdx.z;
  const unsigned short* Bp = (z == 0) ? B0 : (z == 1) ? B1 : B2;
  void* Cp = (z == 0) ? C0 : (z == 1) ? C1 : C2;
  const int mode = (modesel == 0) ? 0 : ((z == 2) ? 2 : 1);
  // Q epilogue scale: 1/sqrt(64) * log2(e)  (attn uses exp2 directly)
  const float escale = (modesel == 1 && z == 0) ? 0.180336879f : 1.0f;

  const int tid = threadIdx.x;
  const int lane = tid & 63, wave = tid >> 6;
  const int bm = blockIdx.y * 128, bn = blockIdx.x * 128;
  const int wr = wave >> 1, wc = wave & 1;           // 2x2 wave grid, 64x64 each
  const int cl = lane & 15, g = lane >> 4;
  // staging: chunks of 512 elems (8 rows x 64 elems); pre-swizzled global slot
  const int ci = lane >> 3, si = lane & 7;
  const int sg = si ^ (ci & 7);

  f32x4 acc[4][4] = {};

  for (int kb = 0; kb < K; kb += 64) {
    __syncthreads();
#pragma unroll
    for (int cc = 0; cc < 4; ++cc) {
      int chunk = wave * 4 + cc;
      int row = chunk * 8 + ci;
      gload16(A  + (size_t)(bm + row) * K + kb + sg * 8, &At[chunk * 512]);
      gload16(Bp + (size_t)(bn + row) * K + kb + sg * 8, &Bt[chunk * 512]);
    }
    __syncthreads();
#pragma unroll
    for (int kc = 0; kc < 2; ++kc) {
      bf16x8 af[4], bfr[4];
#pragma unroll
      for (int mi = 0; mi < 4; ++mi) {
        int row = wr * 64 + mi * 16 + cl;
        int slot = (kc * 4 + g) ^ (row & 7);
        af[mi] = load8(&At[row * 64 + slot * 8]);
      }
#pragma unroll
      for (int ni = 0; ni < 4; ++ni) {
        int row = wc * 64 + ni * 16 + cl;
        int slot = (kc * 4 + g) ^ (row & 7);
        bfr[ni] = load8(&Bt[row * 64 + slot * 8]);
      }
#pragma unroll
      for (int mi = 0; mi < 4; ++mi)
#pragma unroll
        for (int ni = 0; ni < 4; ++ni)
          acc[mi][ni] = __builtin_amdgcn_mfma_f32_16x16x32_bf16(af[mi], bfr[ni], acc[mi][ni], 0, 0, 0);
    }
  }

  // epilogue: C row = (lane>>4)*4 + reg, col = lane&15
  const int r0 = g * 4;
#pragma unroll
  for (int mi = 0; mi < 4; ++mi) {
#pragma unroll
    for (int ni = 0; ni < 4; ++ni) {
      int mg = bm + wr * 64 + mi * 16 + r0;
      int ng = bn + wc * 64 + ni * 16 + cl;
#pragma unroll
      for (int r = 0; r < 4; ++r) {
        float v = acc[mi][ni][r] * escale;
        int m = mg + r;
        if (mode == 0) {
          ((float*)Cp)[(size_t)m * N + ng] = v;
        } else {
          int b = m >> 11, s = m & 2047;        // S=2048
          int h = ng >> 6, d = ng & 63;         // dk=64
          unsigned short* o = (unsigned short*)Cp;
          if (mode == 1) o[((size_t)(b * N_HEADS + h) * S_LEN + s) * 64 + d] = f2bf(v);
          else           o[((size_t)(b * N_HEADS + h) * 64 + d) * S_PAD + s] = f2bf(v);
        }
      }
    }
  }
}

// -- causal flash attention: 32x32 engine, 2-deep ILP k-unroll, in-reg P ------
// 2048 blocks (32 bh x 64 tiles), split-K-4 across 4 waves. No-max exp2
// softmax; interior loop processes TWO k-blocks with interleaved chains.
// Diagonal peeled (only wave 3 masks). Vt rows padded to S_PAD to spread
// the 32-row strided read across all L2 channels (4KB stride camped on one).
__global__ __launch_bounds__(256) void attn_kernel(
    const unsigned short* __restrict__ Qg,
    const unsigned short* __restrict__ Kg,
    const unsigned short* __restrict__ Vtg,
    unsigned short* __restrict__ Og)
{
  __shared__ __align__(16) unsigned short OB[32 * 72];       // merge/output bounce
  __shared__ __align__(16) unsigned int MoB[3][2][8][64];    // waves 0-2 o^T frags (bf16 pairs)
  __shared__ __align__(16) float Lq[4][32];                  // per-wave l (q-layout)

  const int tid = threadIdx.x;
  const int lane = tid & 63, wave = tid >> 6;
  const int l31 = lane & 31, hi = lane >> 5;

  // XCD-contiguous: 4 bh per XCD slot; tiles descend (heavy first)
  const int L = blockIdx.x >> 3;                   // 0..255
  const int bh = (blockIdx.x & 7) * 4 + (L & 3);   // 32 (b,h) pairs
  const int qtile = 63 - (L >> 2);                 // 63..0, heavy first
  const int qt = qtile * 32;

  const size_t qkb = (size_t)bh * S_LEN;
  const int b = bh >> 4, h = bh & 15;

  const int nkb = qtile + 1;
  const int kb0 = (nkb * wave) >> 2;
  const int kb1 = (nkb * (wave + 1)) >> 2;
  const int kend = kb1 - ((wave == 3) ? 1 : 0);    // interior (mask-free) end

  // Q B-frags (col q = qt+l31, dk = f*16 + hi*8 + j)
  bf16x8 bq[4];
#pragma unroll
  for (int f = 0; f < 4; ++f)
    bq[f] = load8(Qg + (qkb + qt + l31) * 64 + f * 16 + hi * 8);

  f32x16 o[2] = {};     // o^T: lane holds q=l31; d = dt*32 + (r&3)+8*(r>>2)+4*hi
  float lpart = 0.f;

  // pointer-bump bases at kb0
  const unsigned short* kp = Kg + (qkb + kb0 * 32 + l31) * 64 + hi * 8;
  const unsigned short* vp = Vtg + ((size_t)bh * 64 + l31) * S_PAD + kb0 * 32 + hi * 8;
  const size_t VD = (size_t)32 * S_PAD;   // dt stride in Vt

  // single mask-free k-block; advances kp/vp
  auto body1 = [&]() {
    bf16x8 kA[4], vA[2][2];
#pragma unroll
    for (int f = 0; f < 4; ++f) kA[f] = load8(kp + f * 16);
#pragma unroll
    for (int kf = 0; kf < 2; ++kf)
#pragma unroll
      for (int dt = 0; dt < 2; ++dt) vA[kf][dt] = load8(vp + dt * VD + kf * 16);
    f32x16 c = {};
    __builtin_amdgcn_s_setprio(1);
#pragma unroll
    for (int f = 0; f < 4; ++f) c = __builtin_amdgcn_mfma_f32_32x32x16_bf16(kA[f], bq[f], c, 0, 0, 0);
    __builtin_amdgcn_s_setprio(0);
    float s0 = 0.f, s1 = 0.f;
#pragma unroll
    for (int r = 0; r < 16; r += 2) {
      c[r] = __builtin_amdgcn_exp2f(c[r]);     s0 += c[r];
      c[r + 1] = __builtin_amdgcn_exp2f(c[r + 1]); s1 += c[r + 1];
    }
    lpart += s0 + s1;
    bf16x8 pb[2];
#pragma unroll
    for (int kf = 0; kf < 2; ++kf) {
      unsigned int x0 = cvtpk(c[8 * kf + 0], c[8 * kf + 1]);
      unsigned int x1 = cvtpk(c[8 * kf + 2], c[8 * kf + 3]);
      unsigned int y0 = cvtpk(c[8 * kf + 4], c[8 * kf + 5]);
      unsigned int y1 = cvtpk(c[8 * kf + 6], c[8 * kf + 7]);
      pl32swap(x0, y0); pl32swap(x1, y1);
      pb[kf] = __builtin_bit_cast(bf16x8, (uintx4){x0, x1, y0, y1});
    }
    __builtin_amdgcn_s_setprio(1);
#pragma unroll
    for (int kf = 0; kf < 2; ++kf)
#pragma unroll
      for (int dt = 0; dt < 2; ++dt)
        o[dt] = __builtin_amdgcn_mfma_f32_32x32x16_bf16(vA[kf][dt], pb[kf], o[dt], 0, 0, 0);
    __builtin_amdgcn_s_setprio(0);
    kp += 2048; vp += 32;
  };

  int kb = kb0;
  // interior: 2-deep unroll, independent chains interleaved
  for (; kb + 2 <= kend; kb += 2) {
    bf16x8 kA[4], vA[2][2];
#pragma unroll
    for (int f = 0; f < 4; ++f) kA[f] = load8(kp + f * 16);
#pragma unroll
    for (int kf = 0; kf < 2; ++kf)
#pragma unroll
      for (int dt = 0; dt < 2; ++dt) vA[kf][dt] = load8(vp + dt * VD + kf * 16);

    f32x16 cA = {};
    __builtin_amdgcn_s_setprio(1);
#pragma unroll
    for (int f = 0; f < 4; ++f) cA = __builtin_amdgcn_mfma_f32_32x32x16_bf16(kA[f], bq[f], cA, 0, 0, 0);
    __builtin_amdgcn_s_setprio(0);

    // issue B's loads while A's QK chain drains
    bf16x8 kB[4], vB[2][2];
#pragma unroll
    for (int f = 0; f < 4; ++f) kB[f] = load8(kp + 2048 + f * 16);
#pragma unroll
    for (int kf = 0; kf < 2; ++kf)
#pragma unroll
      for (int dt = 0; dt < 2; ++dt) vB[kf][dt] = load8(vp + 32 + dt * VD + kf * 16);

    f32x16 cB = {};
    __builtin_amdgcn_s_setprio(1);
#pragma unroll
    for (int f = 0; f < 4; ++f) cB = __builtin_amdgcn_mfma_f32_32x32x16_bf16(kB[f], bq[f], cB, 0, 0, 0);
    __builtin_amdgcn_s_setprio(0);

    // softmax A (overlaps B's QK chain)
    float sA0 = 0.f, sA1 = 0.f;
#pragma unroll
    for (int r = 0; r < 16; r += 2) {
      cA[r] = __builtin_amdgcn_exp2f(cA[r]);       sA0 += cA[r];
      cA[r + 1] = __builtin_amdgcn_exp2f(cA[r + 1]); sA1 += cA[r + 1];
    }
    bf16x8 pbA[2];
#pragma unroll
    for (int kf = 0; kf < 2; ++kf) {
      unsigned int x0 = cvtpk(cA[8 * kf + 0], cA[8 * kf + 1]);
      unsigned int x1 = cvtpk(cA[8 * kf + 2], cA[8 * kf + 3]);
      unsigned int y0 = cvtpk(cA[8 * kf + 4], cA[8 * kf + 5]);
      unsigned int y1 = cvtpk(cA[8 * kf + 6], cA[8 * kf + 7]);
      pl32swap(x0, y0); pl32swap(x1, y1);
      pbA[kf] = __builtin_bit_cast(bf16x8, (uintx4){x0, x1, y0, y1});
    }
    // softmax B
    float sB0 = 0.f, sB1 = 0.f;
#pragma unroll
    for (int r = 0; r < 16; r += 2) {
      cB[r] = __builtin_amdgcn_exp2f(cB[r]);       sB0 += cB[r];
      cB[r + 1] = __builtin_amdgcn_exp2f(cB[r + 1]); sB1 += cB[r + 1];
    }
    bf16x8 pbB[2];
#pragma unroll
    for (int kf = 0; kf < 2; ++kf) {
      unsigned int x0 = cvtpk(cB[8 * kf + 0], cB[8 * kf + 1]);
      unsigned int x1 = cvtpk(cB[8 * kf + 2], cB[8 * kf + 3]);
      unsigned int y0 = cvtpk(cB[8 * kf + 4], cB[8 * kf + 5]);
      unsigned int y1 = cvtpk(cB[8 * kf + 6], cB[8 * kf + 7]);
      pl32swap(x0, y0); pl32swap(x1, y1);
      pbB[kf] = __builtin_bit_cast(bf16x8, (uintx4){x0, x1, y0, y1});
    }
    lpart += (sA0 + sA1) + (sB0 + sB1);

    __builtin_amdgcn_s_setprio(1);
#pragma unroll
    for (int kf = 0; kf < 2; ++kf)
#pragma unroll
      for (int dt = 0; dt < 2; ++dt)
        o[dt] = __builtin_amdgcn_mfma_f32_32x32x16_bf16(vA[kf][dt], pbA[kf], o[dt], 0, 0, 0);
#pragma unroll
    for (int kf = 0; kf < 2; ++kf)
#pragma unroll
      for (int dt = 0; dt < 2; ++dt)
        o[dt] = __builtin_amdgcn_mfma_f32_32x32x16_bf16(vB[kf][dt], pbB[kf], o[dt], 0, 0, 0);
    __builtin_amdgcn_s_setprio(0);

    kp += 4096; vp += 64;
  }
  // interior tail (single, mask-free)
  for (; kb < kend; ++kb) body1();

  // peeled diagonal (wave 3 only): kp/vp already point at kb = nkb-1
  if (wave == 3) {
    const int kbase = (nkb - 1) * 32;
    bf16x8 kA[4], vA[2][2];
#pragma unroll
    for (int f = 0; f < 4; ++f) kA[f] = load8(kp + f * 16);
#pragma unroll
    for (int kf = 0; kf < 2; ++kf)
#pragma unroll
      for (int dt = 0; dt < 2; ++dt) vA[kf][dt] = load8(vp + dt * VD + kf * 16);
    f32x16 c = {};
    __builtin_amdgcn_s_setprio(1);
#pragma unroll
    for (int f = 0; f < 4; ++f) c = __builtin_amdgcn_mfma_f32_32x32x16_bf16(kA[f], bq[f], c, 0, 0, 0);
    __builtin_amdgcn_s_setprio(0);
    int q = qt + l31;
#pragma unroll
    for (int r = 0; r < 16; ++r) {
      int k = kbase + (r & 3) + 8 * (r >> 2) + 4 * hi;
      if (k > q) c[r] = -1e30f;
    }
    float s0 = 0.f, s1 = 0.f;
#pragma unroll
    for (int r = 0; r < 16; r += 2) {
      c[r] = __builtin_amdgcn_exp2f(c[r]);         s0 += c[r];
      c[r + 1] = __builtin_amdgcn_exp2f(c[r + 1]); s1 += c[r + 1];
    }
    lpart += s0 + s1;
    bf16x8 pb[2];
#pragma unroll
    for (int kf = 0; kf < 2; ++kf) {
      unsigned int x0 = cvtpk(c[8 * kf + 0], c[8 * kf + 1]);
      unsigned int x1 = cvtpk(c[8 * kf + 2], c[8 * kf + 3]);
      unsigned int y0 = cvtpk(c[8 * kf + 4], c[8 * kf + 5]);
      unsigned int y1 = cvtpk(c[8 * kf + 6], c[8 * kf + 7]);
      pl32swap(x0, y0); pl32swap(x1, y1);
      pb[kf] = __builtin_bit_cast(bf16x8, (uintx4){x0, x1, y0, y1});
    }
    __builtin_amdgcn_s_setprio(1);
#pragma unroll
    for (int kf = 0; kf < 2; ++kf)
#pragma unroll
      for (int dt = 0; dt < 2; ++dt)
        o[dt] = __builtin_amdgcn_mfma_f32_32x32x16_bf16(vA[kf][dt], pb[kf], o[dt], 0, 0, 0);
    __builtin_amdgcn_s_setprio(0);
  }

  // l: one half-swap reduce; publish in q-layout
  {
    float lf = lpart + __shfl_xor(lpart, 32, 64);
    if (lane < 32) Lq[wave][lane] = lf;
  }
  // waves 0-2 publish o^T fragments (bf16-packed)
  if (wave < 3) {
#pragma unroll
    for (int dt = 0; dt < 2; ++dt)
#pragma unroll
      for (int rp = 0; rp < 8; ++rp)
        MoB[wave][dt][rp][lane] = cvtpk(o[dt][2 * rp], o[dt][2 * rp + 1]);
  }
  __syncthreads();

  if (wave == 3) {
    float lsum = Lq[0][l31] + Lq[1][l31] + Lq[2][l31] + Lq[3][l31];
    float inv = 1.0f / lsum;
#pragma unroll
    for (int dt = 0; dt < 2; ++dt) {
      f32x16 of = o[dt];
#pragma unroll
      for (int w = 0; w < 3; ++w)
#pragma unroll
        for (int rp = 0; rp < 8; ++rp) {
          unsigned int u = MoB[w][dt][rp][lane];
          of[2 * rp]     += bfhi(u & 0xffffu);
          of[2 * rp + 1] += bfhi(u >> 16);
        }
      // OB[q][d]: q = l31 row; d-chunks of 4 at dt*32 + 8*rc + 4*hi
#pragma unroll
      for (int rc = 0; rc < 4; ++rc) {
        unsigned int u0 = cvtpk(of[4 * rc] * inv, of[4 * rc + 1] * inv);
        unsigned int u1 = cvtpk(of[4 * rc + 2] * inv, of[4 * rc + 3] * inv);
        unsigned long long pv = (unsigned long long)u0 | ((unsigned long long)u1 << 32);
        *(unsigned long long*)&OB[l31 * 72 + dt * 32 + 8 * rc + 4 * hi] = pv;
      }
    }
    // coalesced flush: 512 u64 = 32 q-rows x 128B
#pragma unroll
    for (int i = 0; i < 8; ++i) {
      int idx = i * 64 + lane;
      int qr = idx >> 4, c8 = idx & 15;
      unsigned long long v = *(const unsigned long long*)&OB[qr * 72 + c8 * 4];
      *(unsigned long long*)&Og[((size_t)(b * S_LEN + qt + qr)) * D_DIM + h * 64 + c8 * 4] = v;
    }
  }
}

extern "C" void kernel_launch(void* const* d_in, const int* in_sizes, int n_in,
                              void* d_out, int out_size, void* d_ws, size_t ws_size,
                              hipStream_t stream) {
  const float* x  = (const float*)d_in[0];
  const float* Wq = (const float*)d_in[1];
  const float* Wk = (const float*)d_in[2];
  const float* Wv = (const float*)d_in[3];
  const float* Wo = (const float*)d_in[4];

  const int M = M_ROWS, D = D_DIM;

  unsigned short* ws  = (unsigned short*)d_ws;
  unsigned short* xb  = ws;                          // M*D
  unsigned short* wqb = xb  + (size_t)M * D;         // D*D
  unsigned short* wkb = wqb + (size_t)D * D;
  unsigned short* wvb = wkb + (size_t)D * D;
  unsigned short* wob = wvb + (size_t)D * D;
  unsigned short* qb  = wob + (size_t)D * D;         // M*D  [B,H,S,64] (scaled)
  unsigned short* kbf = qb  + (size_t)M * D;         // M*D  [B,H,S,64]
  unsigned short* vtb = kbf + (size_t)M * D;         // 32*64*S_PAD [B,H,64,S_PAD]
  unsigned short* aob = vtb + (size_t)32 * 64 * S_PAD;  // M*D  [B,S,D]

  // 1) convert inputs to bf16 (single fused launch)
  {
    dim3 gc(M * D / 4 / 256, 5);
    cvt5_kernel<<<gc, 256, 0, stream>>>(x, Wq, Wk, Wv, Wo,
                                        xb, wqb, wkb, wvb, wob,
                                        M * D / 4, D * D / 4);
  }

  // 2) fused QKV projections (Q scaled by log2e/8 in epilogue)
  dim3 gq(D / 128, M / 128, 3);
  gemm_bt<<<gq, 256, 0, stream>>>(xb, wqb, wkb, wvb, qb, kbf, vtb, M, D, D, 1);

  // 3) causal flash attention (padded-Vt, 2-deep ILP, split-K-4, 2048 blocks)
  attn_kernel<<<2048, 256, 0, stream>>>(qb, kbf, vtb, aob);

  // 4) output projection -> fp32 d_out
  dim3 go(D / 128, M / 128, 1);
  gemm_bt<<<go, 256, 0, stream>>>(aob, wob, wob, wob, d_out, d_out, d_out, M, D, D, 0);
}

// Round 15
// 113.345 us; speedup vs baseline: 1.2515x; 1.2515x over previous
//
#include <hip/hip_runtime.h>
#include <hip/hip_bf16.h>

// Problem constants: B=2, S=2048, D=1024, H=16, dk=64
#define S_LEN 2048
#define S_PAD 2112
#define D_DIM 1024
#define N_HEADS 16
#define M_ROWS 4096  // B*S

typedef __bf16 bf16x8 __attribute__((ext_vector_type(8)));
typedef float f32x4 __attribute__((ext_vector_type(4)));
typedef float f32x16 __attribute__((ext_vector_type(16)));
typedef unsigned short ushortx8 __attribute__((ext_vector_type(8)));
typedef unsigned int uintx4 __attribute__((ext_vector_type(4)));

__device__ __forceinline__ unsigned short f2bf(float f) {
  unsigned int u = __builtin_bit_cast(unsigned int, f);
  u += 0x7fffu + ((u >> 16) & 1u);   // RNE
  return (unsigned short)(u >> 16);
}

// v_cvt_pk_bf16_f32: packs 2 f32 -> u32 (lo|hi<<16), RNE. No builtin on gfx950.
__device__ __forceinline__ unsigned int cvtpk(float lo, float hi) {
  unsigned int r;
  asm("v_cvt_pk_bf16_f32 %0, %1, %2" : "=v"(r) : "v"(lo), "v"(hi));
  return r;
}

// v_permlane32_swap_b32 a, b: a.lanes[32:63] <-> b.lanes[0:31]
__device__ __forceinline__ void pl32swap(unsigned int& a, unsigned int& b) {
  asm("v_permlane32_swap_b32 %0, %1" : "+v"(a), "+v"(b));
}

__device__ __forceinline__ bf16x8 load8(const unsigned short* p) {
  return __builtin_bit_cast(bf16x8, *(const ushortx8*)p);
}

__device__ __forceinline__ void gload16(const unsigned short* g, unsigned short* l) {
  __builtin_amdgcn_global_load_lds((const __attribute__((address_space(1))) void*)g,
                                   (__attribute__((address_space(3))) void*)l,
                                   16, 0, 0);
}

// ---------------- fp32 -> bf16 convert (fused: x + 4 weights) ----------------
__global__ void cvt5_kernel(const float* __restrict__ s0, const float* __restrict__ s1,
                            const float* __restrict__ s2, const float* __restrict__ s3,
                            const float* __restrict__ s4,
                            unsigned short* __restrict__ d0, unsigned short* __restrict__ d1,
                            unsigned short* __restrict__ d2, unsigned short* __restrict__ d3,
                            unsigned short* __restrict__ d4,
                            int n4x, int n4w) {
  const int y = blockIdx.y;
  const float* s = (y == 0) ? s0 : (y == 1) ? s1 : (y == 2) ? s2 : (y == 3) ? s3 : s4;
  unsigned short* d = (y == 0) ? d0 : (y == 1) ? d1 : (y == 2) ? d2 : (y == 3) ? d3 : d4;
  const int n4 = (y == 0) ? n4x : n4w;
  int i = blockIdx.x * blockDim.x + threadIdx.x;
  if (i < n4) {
    float4 f = ((const float4*)s)[i];
    unsigned int u0 = cvtpk(f.x, f.y), u1 = cvtpk(f.z, f.w);
    unsigned long long packed = (unsigned long long)u0 | ((unsigned long long)u1 << 32);
    ((unsigned long long*)d)[i] = packed;
  }
}

// ---------------- bf16 GEMM: C = A[M,K] * B[N,K]^T ----------------
// mode 0: fp32 row-major [M][N] output
// mode 1: bf16 [B,H,S,64] output (Q,K); Q (z==0) pre-scaled by log2e/sqrt(dk)
// mode 2: bf16 [B,H,64,S_PAD] output (V transposed, padded stride)
__global__ __launch_bounds__(256) void gemm_bt(
    const unsigned short* __restrict__ A,
    const unsigned short* __restrict__ B0,
    const unsigned short* __restrict__ B1,
    const unsigned short* __restrict__ B2,
    void* __restrict__ C0, void* __restrict__ C1, void* __restrict__ C2,
    int M, int N, int K, int modesel)
{
  __shared__ __align__(16) unsigned short At[128 * 64];
  __shared__ __align__(16) unsigned short Bt[128 * 64];

  const int z = blockIdx.z;
  const unsigned short* Bp = (z == 0) ? B0 : (z == 1) ? B1 : B2;
  void* Cp = (z == 0) ? C0 : (z == 1) ? C1 : C2;
  const int mode = (modesel == 0) ? 0 : ((z == 2) ? 2 : 1);
  const float escale = (modesel == 1 && z == 0) ? 0.180336879f : 1.0f;

  const int tid = threadIdx.x;
  const int lane = tid & 63, wave = tid >> 6;
  const int bm = blockIdx.y * 128, bn = blockIdx.x * 128;
  const int wr = wave >> 1, wc = wave & 1;
  const int cl = lane & 15, g = lane >> 4;
  const int ci = lane >> 3, si = lane & 7;
  const int sg = si ^ (ci & 7);

  f32x4 acc[4][4] = {};

  for (int kb = 0; kb < K; kb += 64) {
    __syncthreads();
#pragma unroll
    for (int cc = 0; cc < 4; ++cc) {
      int chunk = wave * 4 + cc;
      int row = chunk * 8 + ci;
      gload16(A  + (size_t)(bm + row) * K + kb + sg * 8, &At[chunk * 512]);
      gload16(Bp + (size_t)(bn + row) * K + kb + sg * 8, &Bt[chunk * 512]);
    }
    __syncthreads();
#pragma unroll
    for (int kc = 0; kc < 2; ++kc) {
      bf16x8 af[4], bfr[4];
#pragma unroll
      for (int mi = 0; mi < 4; ++mi) {
        int row = wr * 64 + mi * 16 + cl;
        int slot = (kc * 4 + g) ^ (row & 7);
        af[mi] = load8(&At[row * 64 + slot * 8]);
      }
#pragma unroll
      for (int ni = 0; ni < 4; ++ni) {
        int row = wc * 64 + ni * 16 + cl;
        int slot = (kc * 4 + g) ^ (row & 7);
        bfr[ni] = load8(&Bt[row * 64 + slot * 8]);
      }
#pragma unroll
      for (int mi = 0; mi < 4; ++mi)
#pragma unroll
        for (int ni = 0; ni < 4; ++ni)
          acc[mi][ni] = __builtin_amdgcn_mfma_f32_16x16x32_bf16(af[mi], bfr[ni], acc[mi][ni], 0, 0, 0);
    }
  }

  const int r0 = g * 4;
#pragma unroll
  for (int mi = 0; mi < 4; ++mi) {
#pragma unroll
    for (int ni = 0; ni < 4; ++ni) {
      int mg = bm + wr * 64 + mi * 16 + r0;
      int ng = bn + wc * 64 + ni * 16 + cl;
#pragma unroll
      for (int r = 0; r < 4; ++r) {
        float v = acc[mi][ni][r] * escale;
        int m = mg + r;
        if (mode == 0) {
          ((float*)Cp)[(size_t)m * N + ng] = v;
        } else {
          int b = m >> 11, s = m & 2047;
          int h = ng >> 6, d = ng & 63;
          unsigned short* o = (unsigned short*)Cp;
          if (mode == 1) o[((size_t)(b * N_HEADS + h) * S_LEN + s) * 64 + d] = f2bf(v);
          else           o[((size_t)(b * N_HEADS + h) * 64 + d) * S_PAD + s] = f2bf(v);
        }
      }
    }
  }
}

// -- causal flash attention: LDS-staged shared K/V, 128q-row blocks -----------
// 256 blocks = 1/CU, perfectly uniform: block owns tile pair (p, 15-p) of 128
// q-rows each -> (p+1)+(16-p) = 17 staged 128-key chunks per block. 4 waves
// share the staged K/V (4x L2 reuse); staging via global_load_lds (coalesced
// 1KB/instr, ~8x fewer L2 transactions than the old per-lane fragment gather
// that pinned every prior variant at 72us). XOR swizzle applied on the GLOBAL
// source (linear LDS dest, rule 21); fragment ds_reads are conflict-free.
// No split-K -> no merge. No-max exp2 softmax (Q pre-scaled log2e/8).
__global__ __launch_bounds__(256) void attn_kernel(
    const unsigned short* __restrict__ Qg,
    const unsigned short* __restrict__ Kg,
    const unsigned short* __restrict__ Vtg,
    unsigned short* __restrict__ Og)
{
  __shared__ __align__(16) unsigned short Kb[2][8192];   // [buf][128 krow x 64 elem]
  __shared__ __align__(16) unsigned short Vb[2][8192];   // [buf][64 drow x 128 key]
  __shared__ __align__(16) unsigned short OB[4][32 * 72];

  const int tid = threadIdx.x;
  const int lane = tid & 63, wave = tid >> 6;
  const int l31 = lane & 31, hi = lane >> 5;

  // 256 blocks: XCD x gets bh {4x..4x+3} (K/V 2MB L2-resident per XCD)
  const int bh = (blockIdx.x & 7) * 4 + ((blockIdx.x >> 3) & 3);
  const int p  = blockIdx.x >> 5;                  // pair 0..7
  const int tA = p, tB = 15 - p;                   // tiles of 128 q-rows
  const size_t qkb = (size_t)bh * S_LEN;
  const int b = bh >> 4, h = bh & 15;

  int cur = 0;

  // ---- staging: coalesced gload_lds, swizzle folded into global source ----
  auto stageK = [&](int buf, int ch) {             // 128 rows x 128B
    const unsigned short* base = Kg + (qkb + (size_t)ch * 128) * 64;
#pragma unroll
    for (int ii = 0; ii < 4; ++ii) {
      int i = wave * 4 + ii;
      int ri = i * 8 + (lane >> 3);
      int e = (((lane & 7) ^ (lane >> 3)) << 3);
      gload16(base + (size_t)ri * 64 + e, &Kb[buf][i * 512]);
    }
  };
  auto stageV = [&](int buf, int ch) {             // 64 rows x 256B
    const unsigned short* base = Vtg + (size_t)bh * 64 * S_PAD + ch * 128;
#pragma unroll
    for (int ii = 0; ii < 4; ++ii) {
      int i = wave * 4 + ii;
      int ri = i * 4 + (lane >> 4);
      int e = (((lane & 15) ^ (ri & 7)) << 3);
      gload16(base + (size_t)ri * S_PAD + e, &Vb[buf][i * 512]);
    }
  };

  const int swz = (l31 & 7) << 3;

  // one 32-key block from staged buffers
  auto kblock = [&](int buf, const bf16x8 (&bq)[4], f32x16 (&o)[2], float& lpart,
                    int j, int jj, bool domask, int qrow) {
    bf16x8 kc[4];
    int krow = j * 32 + l31;
#pragma unroll
    for (int f = 0; f < 4; ++f)
      kc[f] = load8(&Kb[buf][krow * 64 + ((f * 16 + hi * 8) ^ swz)]);
    f32x16 c = {};
    __builtin_amdgcn_s_setprio(1);
#pragma unroll
    for (int f = 0; f < 4; ++f)
      c = __builtin_amdgcn_mfma_f32_32x32x16_bf16(kc[f], bq[f], c, 0, 0, 0);
    __builtin_amdgcn_s_setprio(0);
    if (domask) {
#pragma unroll
      for (int r = 0; r < 16; ++r) {
        int k = jj * 32 + (r & 3) + 8 * (r >> 2) + 4 * hi;
        if (k > qrow) c[r] = -1e30f;
      }
    }
    float s0 = 0.f, s1 = 0.f;
#pragma unroll
    for (int r = 0; r < 16; r += 2) {
      c[r] = __builtin_amdgcn_exp2f(c[r]);         s0 += c[r];
      c[r + 1] = __builtin_amdgcn_exp2f(c[r + 1]); s1 += c[r + 1];
    }
    lpart += s0 + s1;
    bf16x8 pb[2];
#pragma unroll
    for (int kf = 0; kf < 2; ++kf) {
      unsigned int x0 = cvtpk(c[8 * kf + 0], c[8 * kf + 1]);
      unsigned int x1 = cvtpk(c[8 * kf + 2], c[8 * kf + 3]);
      unsigned int y0 = cvtpk(c[8 * kf + 4], c[8 * kf + 5]);
      unsigned int y1 = cvtpk(c[8 * kf + 6], c[8 * kf + 7]);
      pl32swap(x0, y0); pl32swap(x1, y1);
      pb[kf] = __builtin_bit_cast(bf16x8, (uintx4){x0, x1, y0, y1});
    }
    bf16x8 vf[2][2];
#pragma unroll
    for (int kf = 0; kf < 2; ++kf)
#pragma unroll
      for (int dt = 0; dt < 2; ++dt)
        vf[kf][dt] = load8(&Vb[buf][(dt * 32 + l31) * 128 + ((j * 32 + kf * 16 + hi * 8) ^ swz)]);
    __builtin_amdgcn_s_setprio(1);
#pragma unroll
    for (int kf = 0; kf < 2; ++kf)
#pragma unroll
      for (int dt = 0; dt < 2; ++dt)
        o[dt] = __builtin_amdgcn_mfma_f32_32x32x16_bf16(vf[kf][dt], pb[kf], o[dt], 0, 0, 0);
    __builtin_amdgcn_s_setprio(0);
  };

  auto finalize = [&](int qt, f32x16 (&o)[2], float lpart) {
    float lf = lpart + __shfl_xor(lpart, 32, 64);
    float inv = 1.0f / lf;
    unsigned short* W = &OB[wave][0];
#pragma unroll
    for (int dt = 0; dt < 2; ++dt)
#pragma unroll
      for (int rc = 0; rc < 4; ++rc) {
        unsigned int u0 = cvtpk(o[dt][4 * rc] * inv, o[dt][4 * rc + 1] * inv);
        unsigned int u1 = cvtpk(o[dt][4 * rc + 2] * inv, o[dt][4 * rc + 3] * inv);
        unsigned long long pv = (unsigned long long)u0 | ((unsigned long long)u1 << 32);
        *(unsigned long long*)&W[l31 * 72 + dt * 32 + 8 * rc + 4 * hi] = pv;
      }
#pragma unroll
    for (int i = 0; i < 8; ++i) {
      int idx = i * 64 + lane;
      int qr = idx >> 4, c8 = idx & 15;
      unsigned long long v = *(const unsigned long long*)&W[qr * 72 + c8 * 4];
      *(unsigned long long*)&Og[((size_t)(b * S_LEN + qt + wave * 32 + qr)) * D_DIM + h * 64 + c8 * 4] = v;
    }
  };

  // process one 128-row tile; assumes chunk 0 already staged in buf `cur`.
  // stageNext: stage the NEXT tile's chunk 0 during this tile's tail chunk.
  auto process_tile = [&](int t, int qt, bool stageNext) {
    bf16x8 bq[4];
#pragma unroll
    for (int f = 0; f < 4; ++f)
      bq[f] = load8(Qg + (qkb + qt + wave * 32 + l31) * 64 + f * 16 + hi * 8);
    f32x16 o[2] = {};
    float lpart = 0.f;

    for (int ch = 0; ch < t; ++ch) {               // full (mask-free) chunks
      stageK(cur ^ 1, ch + 1);
      stageV(cur ^ 1, ch + 1);
#pragma unroll
      for (int j = 0; j < 4; ++j)
        kblock(cur, bq, o, lpart, j, 0, false, 0);
      __syncthreads();
      cur ^= 1;
    }
    // tail chunk (ch == t): wave w computes j = 0..w, diagonal mask at j == w
    if (stageNext) { stageK(cur ^ 1, 0); stageV(cur ^ 1, 0); }
    int qrow = qt + wave * 32 + l31;
    for (int j = 0; j <= wave; ++j)
      kblock(cur, bq, o, lpart, j, 4 * t + j, j == wave, qrow);
    finalize(qt, o, lpart);                        // overlaps next-tile staging
    __syncthreads();
    cur ^= 1;
  };

  // prologue: stage tile A chunk 0
  stageK(0, 0); stageV(0, 0);
  __syncthreads();
  process_tile(tA, tA * 128, true);
  process_tile(tB, tB * 128, false);
}

extern "C" void kernel_launch(void* const* d_in, const int* in_sizes, int n_in,
                              void* d_out, int out_size, void* d_ws, size_t ws_size,
                              hipStream_t stream) {
  const float* x  = (const float*)d_in[0];
  const float* Wq = (const float*)d_in[1];
  const float* Wk = (const float*)d_in[2];
  const float* Wv = (const float*)d_in[3];
  const float* Wo = (const float*)d_in[4];

  const int M = M_ROWS, D = D_DIM;

  unsigned short* ws  = (unsigned short*)d_ws;
  unsigned short* xb  = ws;                          // M*D
  unsigned short* wqb = xb  + (size_t)M * D;         // D*D
  unsigned short* wkb = wqb + (size_t)D * D;
  unsigned short* wvb = wkb + (size_t)D * D;
  unsigned short* wob = wvb + (size_t)D * D;
  unsigned short* qb  = wob + (size_t)D * D;         // M*D  [B,H,S,64] (scaled)
  unsigned short* kbf = qb  + (size_t)M * D;         // M*D  [B,H,S,64]
  unsigned short* vtb = kbf + (size_t)M * D;         // 32*64*S_PAD [B,H,64,S_PAD]
  unsigned short* aob = vtb + (size_t)32 * 64 * S_PAD;  // M*D  [B,S,D]

  // 1) convert inputs to bf16 (single fused launch)
  {
    dim3 gc(M * D / 4 / 256, 5);
    cvt5_kernel<<<gc, 256, 0, stream>>>(x, Wq, Wk, Wv, Wo,
                                        xb, wqb, wkb, wvb, wob,
                                        M * D / 4, D * D / 4);
  }

  // 2) fused QKV projections (Q scaled by log2e/8 in epilogue)
  dim3 gq(D / 128, M / 128, 3);
  gemm_bt<<<gq, 256, 0, stream>>>(xb, wqb, wkb, wvb, qb, kbf, vtb, M, D, D, 1);

  // 3) causal flash attention (LDS-staged shared K/V, 256 uniform blocks)
  attn_kernel<<<256, 256, 0, stream>>>(qb, kbf, vtb, aob);

  // 4) output projection -> fp32 d_out
  dim3 go(D / 128, M / 128, 1);
  gemm_bt<<<go, 256, 0, stream>>>(aob, wob, wob, wob, d_out, d_out, d_out, M, D, D, 0);
}